// Round 11
// baseline (80.965 us; speedup 1.0000x reference)
//
#include <hip/hip_runtime.h>

#define GRID_N 16384
#define NLAYERS 8
#define NPOS 32
#define BATCH 32
#define MW 4096          // output width
#define TILE 32
#define HALO 16          // 2 * NLAYERS
#define WBUF 64          // TILE + 2*HALO = one wave of column slots
#define ROWP 36          // gate row stride: 144B; b128 is 16-lane-phased -> 2-way max = free

typedef float f2 __attribute__((ext_vector_type(2)));

// DPP wave shifts: data from lane n-1 / n+1 (boundary lanes read 0; halo absorbs).
__device__ __forceinline__ float dpp_shr1(float v) {   // lane n <- lane n-1
    return __builtin_bit_cast(float, __builtin_amdgcn_update_dpp(
        0, __builtin_bit_cast(int, v), 0x138, 0xF, 0xF, true));
}
__device__ __forceinline__ float dpp_shl1(float v) {   // lane n <- lane n+1
    return __builtin_bit_cast(float, __builtin_amdgcn_update_dpp(
        0, __builtin_bit_cast(int, v), 0x130, 0xF, 0xF, true));
}
__device__ __forceinline__ f2 shr1(f2 v) { f2 r; r.x = dpp_shr1(v.x); r.y = dpp_shr1(v.y); return r; }
__device__ __forceinline__ f2 shl1(f2 v) { f2 r; r.x = dpp_shl1(v.x); r.y = dpp_shl1(v.y); return r; }

__device__ __forceinline__ float sigm(float v) {
    return __builtin_amdgcn_rcpf(1.0f + __expf(-v));
}

// v11 = v10 core + FULL gate prefetch at t=0 + 4-layer gate staging.
// R9/R10 differential: K = warm 9.4 + cold 5.9us; the cold part is 26MB of
// first-touch gate fetch that the rolling 1-group prefetch serialized against
// compute. Now all 32 gate loads/wave (4 cols x 8 layers) are issued in one
// burst before anything else -> the whole 26MB streams at device BW while
// layers 0-3 compute; compiler's oldest-first vmcnt waits pipeline the
// consumption. twl[4] staging (36.9KB, 2 blocks/CU) -> 3 barriers total.
// Skeleton: 512 blocks x 512 threads, wave = 4 batches x 64 col-slots,
// state in VGPRs via DPP, s4-first chunked lerp tree (DS/VALU interleave).
__global__ __launch_bounds__(512, 4) void ASIC_44186623541335_kernel(
    const float* __restrict__ x,    // (32, 4096)
    const float* __restrict__ tg,   // (8, 32, 16384) raw logits
    float* __restrict__ out)        // (32, 4096)
{
    __shared__ __align__(16) float twl[4][WBUF][ROWP];   // 36.9 KB, gates only

    const int tid = threadIdx.x;
    const int tx  = tid & 63;        // column slot (lane)
    const int w   = tid >> 6;        // wave 0..7 -> batches 4w..4w+3, gate cols 4w..4w+3
    const int c0  = 4 * w;
    const int start = blockIdx.x * TILE;
    const int gcol  = (start - HALO + tx) & (GRID_N - 1);

    // ---- issue ALL gate loads now: 4 gate-columns x 8 layers, oldest-first
    //      order = consumption order (layer-major). 26MB in flight at t=0. ----
    float pf[32];
    #pragma unroll
    for (int l = 0; l < NLAYERS; ++l)
        #pragma unroll
        for (int k = 0; k < 4; ++k)
            pf[l * 4 + k] = tg[((size_t)l * NPOS + c0 + k) * GRID_N + gcol];

    // ---- init state IN REGISTERS: embed x at stride 4, zeros elsewhere ----
    f2 S[2];
    {
        const bool on = (gcol & 3) == 0;
        const int  m  = gcol >> 2;
        #pragma unroll
        for (int q = 0; q < 2; ++q) {
            f2 v = {0.0f, 0.0f};
            if (on) {
                v.x = x[(c0 + 2 * q)     * MW + m];
                v.y = x[(c0 + 2 * q + 1) * MW + m];
            }
            S[q] = v;
        }
    }

    // ---- stage layers 0..3 (consumes pf[0..15]; waits only on those) ----
    #pragma unroll
    for (int l4 = 0; l4 < 4; ++l4) {
        float4 sg;
        sg.x = sigm(pf[l4 * 4 + 0]);
        sg.y = sigm(pf[l4 * 4 + 1]);
        sg.z = sigm(pf[l4 * 4 + 2]);
        sg.w = sigm(pf[l4 * 4 + 3]);
        *(float4*)&twl[l4][tx][c0] = sg;
    }
    __syncthreads();   // barrier 1: gates(0..3) visible

    for (int l = 0; l < NLAYERS; ++l) {
        // neighbor states via DPP wave shifts (VALU, independent of LDS)
        f2 s0v[2], s1v[2], s3v[2], s4v[2];
        #pragma unroll
        for (int q = 0; q < 2; ++q) {
            s1v[q] = shr1(S[q]);      // column n-1
            s0v[q] = shr1(s1v[q]);    // column n-2
            s3v[q] = shl1(S[q]);      // column n+1
            s4v[q] = shl1(s3v[q]);    // column n+2
        }

        // level 0 (contract s4): chunk-wise -- each b128 feeds 4 lerps
        // per batch-pair immediately (fine-grained lgkmcnt interleave).
        f2 u0[16], u1[16];
        #pragma unroll
        for (int k = 0; k < 8; ++k) {
            const float4 t4 = *(const float4*)&twl[l & 3][tx][4 * k];
            const float dA = t4.y - t4.x;    // d[2k]   (batch-invariant)
            const float dB = t4.w - t4.z;    // d[2k+1]
            u0[2 * k]     = __builtin_elementwise_fma(s4v[0], (f2)dA, (f2)t4.x);
            u0[2 * k + 1] = __builtin_elementwise_fma(s4v[0], (f2)dB, (f2)t4.z);
            u1[2 * k]     = __builtin_elementwise_fma(s4v[1], (f2)dA, (f2)t4.x);
            u1[2 * k + 1] = __builtin_elementwise_fma(s4v[1], (f2)dB, (f2)t4.z);
        }

        // levels 1..4: contract s3, s2(center), s1, s0 — adjacent pairs
        #pragma unroll
        for (int q = 0; q < 2; ++q) {
            f2* u = q ? u1 : u0;
            #pragma unroll
            for (int r = 0; r < 8; ++r)
                u[r] = __builtin_elementwise_fma(s3v[q], u[2 * r + 1] - u[2 * r], u[2 * r]);
            #pragma unroll
            for (int r = 0; r < 4; ++r)
                u[r] = __builtin_elementwise_fma(S[q],   u[2 * r + 1] - u[2 * r], u[2 * r]);
            #pragma unroll
            for (int r = 0; r < 2; ++r)
                u[r] = __builtin_elementwise_fma(s1v[q], u[2 * r + 1] - u[2 * r], u[2 * r]);
            f2 rv = __builtin_elementwise_fma(s0v[q], u[1] - u[0], u[0]);
            rv = __builtin_elementwise_min(__builtin_elementwise_max(rv, (f2)0.0f), (f2)1.0f);
            S[q] = rv;
        }

        if (l == 3) {
            __syncthreads();   // barrier 2: all waves done reading gates(0..3)
            // stage layers 4..7 from the long-lived prefetch regs
            #pragma unroll
            for (int l4 = 0; l4 < 4; ++l4) {
                float4 sg;
                sg.x = sigm(pf[16 + l4 * 4 + 0]);
                sg.y = sigm(pf[16 + l4 * 4 + 1]);
                sg.z = sigm(pf[16 + l4 * 4 + 2]);
                sg.w = sigm(pf[16 + l4 * 4 + 3]);
                *(float4*)&twl[l4][tx][c0] = sg;
            }
            __syncthreads();   // barrier 3: gates(4..7) visible
        }
    }

    // ---- output straight from registers: state[:, ::4] for owned columns ----
    const int rel = tx - HALO;
    if (rel >= 0 && rel < TILE && (rel & 3) == 0) {
        const int m = (start >> 2) + (rel >> 2);
        out[(c0 + 0) * MW + m] = S[0].x;
        out[(c0 + 1) * MW + m] = S[0].y;
        out[(c0 + 2) * MW + m] = S[1].x;
        out[(c0 + 3) * MW + m] = S[1].y;
    }
}

extern "C" void kernel_launch(void* const* d_in, const int* in_sizes, int n_in,
                              void* d_out, int out_size, void* d_ws, size_t ws_size,
                              hipStream_t stream) {
    const float* x  = (const float*)d_in[0];   // (32, 4096)
    const float* tg = (const float*)d_in[1];   // (8, 32, 16384)
    float* out = (float*)d_out;                // (32, 4096)
    ASIC_44186623541335_kernel<<<GRID_N / TILE, 512, 0, stream>>>(x, tg, out);
}

// Round 12
// 80.289 us; speedup vs baseline: 1.0084x; 1.0084x over previous
//
#include <hip/hip_runtime.h>

#define GRID_N 16384
#define NLAYERS 8
#define NPOS 32
#define BATCH 32
#define MW 4096          // output width
#define TILE 32
#define HALO 16          // 2 * NLAYERS
#define WBUF 64          // TILE + 2*HALO = one wave of column slots
#define ROWP 36          // gate row stride: 144B; b128 is 16-lane-phased -> 2-way max = free

typedef float f2 __attribute__((ext_vector_type(2)));

// DPP wave shifts: data from lane n-1 / n+1 (boundary lanes read 0; halo absorbs).
__device__ __forceinline__ float dpp_shr1(float v) {   // lane n <- lane n-1
    return __builtin_bit_cast(float, __builtin_amdgcn_update_dpp(
        0, __builtin_bit_cast(int, v), 0x138, 0xF, 0xF, true));
}
__device__ __forceinline__ float dpp_shl1(float v) {   // lane n <- lane n+1
    return __builtin_bit_cast(float, __builtin_amdgcn_update_dpp(
        0, __builtin_bit_cast(int, v), 0x130, 0xF, 0xF, true));
}
__device__ __forceinline__ f2 shr1(f2 v) { f2 r; r.x = dpp_shr1(v.x); r.y = dpp_shr1(v.y); return r; }
__device__ __forceinline__ f2 shl1(f2 v) { f2 r; r.x = dpp_shl1(v.x); r.y = dpp_shl1(v.y); return r; }

__device__ __forceinline__ float sigm(float v) {
    return __builtin_amdgcn_rcpf(1.0f + __expf(-v));
}

// LDS-only barrier: __syncthreads() compiles to `s_waitcnt vmcnt(0)
// lgkmcnt(0); s_barrier`, which drains ALL in-flight global loads (this is
// what killed v11's t=0 prefetch). Here the only cross-wave data is LDS
// (twl staging), so lgkmcnt(0) visibility suffices; in-flight global gate
// loads are consumed by their own issuing wave (compiler inserts vmcnt
// waits at consumption) and may legally stay in flight across the barrier.
__device__ __forceinline__ void barrier_lds_only() {
    asm volatile("s_waitcnt lgkmcnt(0)\n\ts_barrier" ::: "memory");
}

// v12 = v11 (full t=0 gate prefetch, twl[4], 3 barriers) FIXED:
//  (1) x loads issued FIRST (oldest) so state-init never forces a drain;
//  (2) barriers are lgkm-only -> pf[16..31] stream across barrier 1 and
//      hide under layers 0-3 compute (true fetch/compute overlap, the
//      hipBLASLt-style "vmcnt never 0" pipeline).
// Skeleton: 512 blocks x 512 threads (2 blocks/CU, 4 waves/SIMD), wave =
// 4 batches x 64 col-slots, state in VGPRs via DPP, s4-first chunked tree.
__global__ __launch_bounds__(512, 4) void ASIC_44186623541335_kernel(
    const float* __restrict__ x,    // (32, 4096)
    const float* __restrict__ tg,   // (8, 32, 16384) raw logits
    float* __restrict__ out)        // (32, 4096)
{
    __shared__ __align__(16) float twl[4][WBUF][ROWP];   // 36.9 KB, gates only

    const int tid = threadIdx.x;
    const int tx  = tid & 63;        // column slot (lane)
    const int w   = tid >> 6;        // wave 0..7 -> batches 4w..4w+3, gate cols 4w..4w+3
    const int c0  = 4 * w;
    const int start = blockIdx.x * TILE;
    const int gcol  = (start - HALO + tx) & (GRID_N - 1);

    // ---- (oldest) x loads: consumed by state init without touching gates ----
    const bool on = (gcol & 3) == 0;
    const int  m  = gcol >> 2;
    float xv[4];
    #pragma unroll
    for (int k = 0; k < 4; ++k)
        xv[k] = on ? x[(c0 + k) * MW + m] : 0.0f;

    // ---- issue ALL gate loads: 4 gate-columns x 8 layers, oldest-first =
    //      consumption order. 26MB in flight; consuming pf[15] waits only
    //      vmcnt(16), so pf[16..31] keep streaming during layers 0-3. ----
    float pf[32];
    #pragma unroll
    for (int l = 0; l < NLAYERS; ++l)
        #pragma unroll
        for (int k = 0; k < 4; ++k)
            pf[l * 4 + k] = tg[((size_t)l * NPOS + c0 + k) * GRID_N + gcol];

    // ---- init state IN REGISTERS: embed x at stride 4, zeros elsewhere ----
    f2 S[2];
    S[0].x = xv[0]; S[0].y = xv[1];
    S[1].x = xv[2]; S[1].y = xv[3];

    // ---- stage layers 0..3 (consumes pf[0..15]; fine-grained vmcnt) ----
    #pragma unroll
    for (int l4 = 0; l4 < 4; ++l4) {
        float4 sg;
        sg.x = sigm(pf[l4 * 4 + 0]);
        sg.y = sigm(pf[l4 * 4 + 1]);
        sg.z = sigm(pf[l4 * 4 + 2]);
        sg.w = sigm(pf[l4 * 4 + 3]);
        *(float4*)&twl[l4][tx][c0] = sg;
    }
    barrier_lds_only();   // barrier 1: gates(0..3) visible; pf[16..31] still in flight

    for (int l = 0; l < NLAYERS; ++l) {
        // neighbor states via DPP wave shifts (VALU, independent of LDS)
        f2 s0v[2], s1v[2], s3v[2], s4v[2];
        #pragma unroll
        for (int q = 0; q < 2; ++q) {
            s1v[q] = shr1(S[q]);      // column n-1
            s0v[q] = shr1(s1v[q]);    // column n-2
            s3v[q] = shl1(S[q]);      // column n+1
            s4v[q] = shl1(s3v[q]);    // column n+2
        }

        // level 0 (contract s4): chunk-wise -- each b128 feeds 4 lerps
        // per batch-pair immediately (fine-grained lgkmcnt interleave).
        f2 u0[16], u1[16];
        #pragma unroll
        for (int k = 0; k < 8; ++k) {
            const float4 t4 = *(const float4*)&twl[l & 3][tx][4 * k];
            const float dA = t4.y - t4.x;    // d[2k]   (batch-invariant)
            const float dB = t4.w - t4.z;    // d[2k+1]
            u0[2 * k]     = __builtin_elementwise_fma(s4v[0], (f2)dA, (f2)t4.x);
            u0[2 * k + 1] = __builtin_elementwise_fma(s4v[0], (f2)dB, (f2)t4.z);
            u1[2 * k]     = __builtin_elementwise_fma(s4v[1], (f2)dA, (f2)t4.x);
            u1[2 * k + 1] = __builtin_elementwise_fma(s4v[1], (f2)dB, (f2)t4.z);
        }

        // levels 1..4: contract s3, s2(center), s1, s0 — adjacent pairs
        #pragma unroll
        for (int q = 0; q < 2; ++q) {
            f2* u = q ? u1 : u0;
            #pragma unroll
            for (int r = 0; r < 8; ++r)
                u[r] = __builtin_elementwise_fma(s3v[q], u[2 * r + 1] - u[2 * r], u[2 * r]);
            #pragma unroll
            for (int r = 0; r < 4; ++r)
                u[r] = __builtin_elementwise_fma(S[q],   u[2 * r + 1] - u[2 * r], u[2 * r]);
            #pragma unroll
            for (int r = 0; r < 2; ++r)
                u[r] = __builtin_elementwise_fma(s1v[q], u[2 * r + 1] - u[2 * r], u[2 * r]);
            f2 rv = __builtin_elementwise_fma(s0v[q], u[1] - u[0], u[0]);
            rv = __builtin_elementwise_min(__builtin_elementwise_max(rv, (f2)0.0f), (f2)1.0f);
            S[q] = rv;
        }

        if (l == 3) {
            barrier_lds_only();   // barrier 2: all waves done reading gates(0..3)
            // stage layers 4..7 from the long-lived prefetch regs (vmcnt
            // waits hit here, but the loads have been streaming ~layers 0-3)
            #pragma unroll
            for (int l4 = 0; l4 < 4; ++l4) {
                float4 sg;
                sg.x = sigm(pf[16 + l4 * 4 + 0]);
                sg.y = sigm(pf[16 + l4 * 4 + 1]);
                sg.z = sigm(pf[16 + l4 * 4 + 2]);
                sg.w = sigm(pf[16 + l4 * 4 + 3]);
                *(float4*)&twl[l4][tx][c0] = sg;
            }
            barrier_lds_only();   // barrier 3: gates(4..7) visible
        }
    }

    // ---- output straight from registers: state[:, ::4] for owned columns ----
    const int rel = tx - HALO;
    if (rel >= 0 && rel < TILE && (rel & 3) == 0) {
        const int mo = (start >> 2) + (rel >> 2);
        out[(c0 + 0) * MW + mo] = S[0].x;
        out[(c0 + 1) * MW + mo] = S[0].y;
        out[(c0 + 2) * MW + mo] = S[1].x;
        out[(c0 + 3) * MW + mo] = S[1].y;
    }
}

extern "C" void kernel_launch(void* const* d_in, const int* in_sizes, int n_in,
                              void* d_out, int out_size, void* d_ws, size_t ws_size,
                              hipStream_t stream) {
    const float* x  = (const float*)d_in[0];   // (32, 4096)
    const float* tg = (const float*)d_in[1];   // (8, 32, 16384)
    float* out = (float*)d_out;                // (32, 4096)
    ASIC_44186623541335_kernel<<<GRID_N / TILE, 512, 0, stream>>>(x, tg, out);
}

// Round 13
// 79.701 us; speedup vs baseline: 1.0159x; 1.0074x over previous
//
#include <hip/hip_runtime.h>

#define GRID_N 16384
#define NLAYERS 8
#define NPOS 32
#define BATCH 32
#define MW 4096          // output width
#define TILE 32
#define HALO 16          // 2 * NLAYERS
#define WBUF 64          // TILE + 2*HALO = one wave of column slots
#define ROWP 36          // gate row stride: 144B; b128 is 16-lane-phased -> 2-way max = free

typedef float f2 __attribute__((ext_vector_type(2)));

// DPP wave shifts: data from lane n-1 / n+1 (boundary lanes read 0; halo absorbs).
__device__ __forceinline__ float dpp_shr1(float v) {   // lane n <- lane n-1
    return __builtin_bit_cast(float, __builtin_amdgcn_update_dpp(
        0, __builtin_bit_cast(int, v), 0x138, 0xF, 0xF, true));
}
__device__ __forceinline__ float dpp_shl1(float v) {   // lane n <- lane n+1
    return __builtin_bit_cast(float, __builtin_amdgcn_update_dpp(
        0, __builtin_bit_cast(int, v), 0x130, 0xF, 0xF, true));
}
__device__ __forceinline__ f2 shr1(f2 v) { f2 r; r.x = dpp_shr1(v.x); r.y = dpp_shr1(v.y); return r; }
__device__ __forceinline__ f2 shl1(f2 v) { f2 r; r.x = dpp_shl1(v.x); r.y = dpp_shl1(v.y); return r; }

__device__ __forceinline__ float sigm(float v) {
    return __builtin_amdgcn_rcpf(1.0f + __expf(-v));
}

// LDS-only barrier: __syncthreads() emits `s_waitcnt vmcnt(0) lgkmcnt(0);
// s_barrier` -- the vmcnt(0) drains ALL in-flight global loads at every
// barrier, serializing the gate prefetch against compute. All our barriers
// guard only LDS (twl staging); global gate loads are consumed by the wave
// that issued them (compiler inserts vmcnt waits at consumption), so they
// may legally remain in flight across the barrier.
__device__ __forceinline__ void barrier_lds_only() {
    asm volatile("s_waitcnt lgkmcnt(0)\n\ts_barrier" ::: "memory");
}

// v13 = v10 (best: rolling 2-layer gate cadence, s4-first chunked tree)
//  + drain-free lgkm-only barriers (v12's one good idea)
//  + double-buffered prefetch regs (pfA/pfB): group g+2's 8 loads issue
//    BEFORE the sigmoid consuming group g+1's regs -> every load burst has
//    ~2 layers of compute in flight ahead of its vmcnt wait, never drained.
// Skeleton: 512 blocks x 512 threads (2 blocks/CU, 4 waves/SIMD), wave =
// 4 batches x 64 col-slots, state in VGPRs via DPP, twl[2] (18.4 KB).
__global__ __launch_bounds__(512, 4) void ASIC_44186623541335_kernel(
    const float* __restrict__ x,    // (32, 4096)
    const float* __restrict__ tg,   // (8, 32, 16384) raw logits
    float* __restrict__ out)        // (32, 4096)
{
    __shared__ __align__(16) float twl[2][WBUF][ROWP];   // 18.4 KB, gates only

    const int tid = threadIdx.x;
    const int tx  = tid & 63;        // column slot (lane)
    const int w   = tid >> 6;        // wave 0..7 -> batches 4w..4w+3, gate cols 4w..4w+3
    const int c0  = 4 * w;
    const int start = blockIdx.x * TILE;
    const int gcol  = (start - HALO + tx) & (GRID_N - 1);

    // ---- x loads first (oldest), then group-0 gate loads ----
    const bool on = (gcol & 3) == 0;
    const int  m  = gcol >> 2;
    float xv[4];
    #pragma unroll
    for (int k = 0; k < 4; ++k)
        xv[k] = on ? x[(c0 + k) * MW + m] : 0.0f;

    float pfA[8], pfB[8];            // double-buffered prefetch regs
    #pragma unroll
    for (int ll = 0; ll < 2; ++ll)
        #pragma unroll
        for (int k = 0; k < 4; ++k)
            pfA[ll * 4 + k] = tg[((size_t)ll * NPOS + c0 + k) * GRID_N + gcol];
    // issue group-1 loads immediately too (independent regs)
    #pragma unroll
    for (int ll = 0; ll < 2; ++ll)
        #pragma unroll
        for (int k = 0; k < 4; ++k)
            pfB[ll * 4 + k] = tg[((size_t)(2 + ll) * NPOS + c0 + k) * GRID_N + gcol];

    // ---- init state IN REGISTERS ----
    f2 S[2];
    S[0].x = xv[0]; S[0].y = xv[1];
    S[1].x = xv[2]; S[1].y = xv[3];

    // ---- stage group 0 (waits only on pfA) ----
    #pragma unroll
    for (int ll = 0; ll < 2; ++ll) {
        float4 sg;
        sg.x = sigm(pfA[ll * 4 + 0]);
        sg.y = sigm(pfA[ll * 4 + 1]);
        sg.z = sigm(pfA[ll * 4 + 2]);
        sg.w = sigm(pfA[ll * 4 + 3]);
        *(float4*)&twl[ll][tx][c0] = sg;
    }
    // issue group-2 loads into the now-free pfA BEFORE any barrier
    #pragma unroll
    for (int ll = 0; ll < 2; ++ll)
        #pragma unroll
        for (int k = 0; k < 4; ++k)
            pfA[ll * 4 + k] = tg[((size_t)(4 + ll) * NPOS + c0 + k) * GRID_N + gcol];
    barrier_lds_only();   // group-0 gates visible; pfB/pfA bursts stay in flight

    #pragma unroll
    for (int g = 0; g < 4; ++g) {          // 4 groups of 2 layers
        #pragma unroll
        for (int ll = 0; ll < 2; ++ll) {
            // neighbor states via DPP wave shifts (VALU, independent of LDS)
            f2 s0v[2], s1v[2], s3v[2], s4v[2];
            #pragma unroll
            for (int q = 0; q < 2; ++q) {
                s1v[q] = shr1(S[q]);      // column n-1
                s0v[q] = shr1(s1v[q]);    // column n-2
                s3v[q] = shl1(S[q]);      // column n+1
                s4v[q] = shl1(s3v[q]);    // column n+2
            }

            // level 0 (contract s4): chunk-wise -- each b128 feeds 4 lerps
            // per batch-pair immediately (fine-grained lgkmcnt interleave).
            f2 u0[16], u1[16];
            #pragma unroll
            for (int k = 0; k < 8; ++k) {
                const float4 t4 = *(const float4*)&twl[ll][tx][4 * k];
                const float dA = t4.y - t4.x;    // d[2k]   (batch-invariant)
                const float dB = t4.w - t4.z;    // d[2k+1]
                u0[2 * k]     = __builtin_elementwise_fma(s4v[0], (f2)dA, (f2)t4.x);
                u0[2 * k + 1] = __builtin_elementwise_fma(s4v[0], (f2)dB, (f2)t4.z);
                u1[2 * k]     = __builtin_elementwise_fma(s4v[1], (f2)dA, (f2)t4.x);
                u1[2 * k + 1] = __builtin_elementwise_fma(s4v[1], (f2)dB, (f2)t4.z);
            }

            // levels 1..4: contract s3, s2(center), s1, s0 — adjacent pairs
            #pragma unroll
            for (int q = 0; q < 2; ++q) {
                f2* u = q ? u1 : u0;
                #pragma unroll
                for (int r = 0; r < 8; ++r)
                    u[r] = __builtin_elementwise_fma(s3v[q], u[2 * r + 1] - u[2 * r], u[2 * r]);
                #pragma unroll
                for (int r = 0; r < 4; ++r)
                    u[r] = __builtin_elementwise_fma(S[q],   u[2 * r + 1] - u[2 * r], u[2 * r]);
                #pragma unroll
                for (int r = 0; r < 2; ++r)
                    u[r] = __builtin_elementwise_fma(s1v[q], u[2 * r + 1] - u[2 * r], u[2 * r]);
                f2 rv = __builtin_elementwise_fma(s0v[q], u[1] - u[0], u[0]);
                rv = __builtin_elementwise_min(__builtin_elementwise_max(rv, (f2)0.0f), (f2)1.0f);
                S[q] = rv;
            }
        }

        if (g < 3) {
            barrier_lds_only();   // all waves done reading this group's gates
            // stage next group from the bank loaded 2 groups ago (g even: pfB
            // holds g+1; g odd: pfA) -- its loads have had ~2 layers to land.
            float* pfs = (g & 1) ? pfA : pfB;
            #pragma unroll
            for (int ll = 0; ll < 2; ++ll) {
                float4 sg;
                sg.x = sigm(pfs[ll * 4 + 0]);
                sg.y = sigm(pfs[ll * 4 + 1]);
                sg.z = sigm(pfs[ll * 4 + 2]);
                sg.w = sigm(pfs[ll * 4 + 3]);
                *(float4*)&twl[ll][tx][c0] = sg;
            }
            if (g < 1) {          // issue group-3 loads into the free bank
                #pragma unroll
                for (int ll = 0; ll < 2; ++ll)
                    #pragma unroll
                    for (int k = 0; k < 4; ++k)
                        pfB[ll * 4 + k] = tg[((size_t)(6 + ll) * NPOS + c0 + k) * GRID_N + gcol];
            }
            barrier_lds_only();   // next group's gates visible
        }
    }

    // ---- output straight from registers: state[:, ::4] for owned columns ----
    const int rel = tx - HALO;
    if (rel >= 0 && rel < TILE && (rel & 3) == 0) {
        const int mo = (start >> 2) + (rel >> 2);
        out[(c0 + 0) * MW + mo] = S[0].x;
        out[(c0 + 1) * MW + mo] = S[0].y;
        out[(c0 + 2) * MW + mo] = S[1].x;
        out[(c0 + 3) * MW + mo] = S[1].y;
    }
}

extern "C" void kernel_launch(void* const* d_in, const int* in_sizes, int n_in,
                              void* d_out, int out_size, void* d_ws, size_t ws_size,
                              hipStream_t stream) {
    const float* x  = (const float*)d_in[0];   // (32, 4096)
    const float* tg = (const float*)d_in[1];   // (8, 32, 16384)
    float* out = (float*)d_out;                // (32, 4096)
    ASIC_44186623541335_kernel<<<GRID_N / TILE, 512, 0, stream>>>(x, tg, out);
}